// Round 6
// baseline (1521.586 us; speedup 1.0000x reference)
//
#include <hip/hip_runtime.h>
#include <hip/hip_bf16.h>
#include <math.h>

#define BB 2
#define LL 1024
#define DIM 512
#define NL 6
#define DI 1024
#define DS 16
#define DC 4
#define DR 32
#define VOCAB 32000
#define M_ROWS (BB * LL)   // 2048
#define CCH 64             // scan chunks
#define CHLEN (LL / CCH)   // 16
#define KSPLIT 8           // x_proj K-split

typedef unsigned short u16;
typedef __attribute__((ext_vector_type(8))) short bf16x8;
typedef __attribute__((ext_vector_type(4))) float f32x4;

__device__ __forceinline__ u16 f2bf(float f) {
    unsigned u = __float_as_uint(f);
    u += 0x7FFF + ((u >> 16) & 1);       // round-to-nearest-even
    return (u16)(u >> 16);
}
// LDS chunk swizzle: row r, 16B-chunk c -> c ^ ((r>>1)&3)  (involution)
#define SWZ(r, c) ((c) ^ (((r) >> 1) & 3))

// ---------------------------------------------------------------------------
// fused fp32 -> bf16 weight cast (lm_w, in_w, ow, xpw)
// group counts (8 elems each): 2048000, 786432, 393216, 49152 -> 3276800
// ---------------------------------------------------------------------------
__global__ __launch_bounds__(256) void cast_all(const float* __restrict__ lm,
                                                const float* __restrict__ inw,
                                                const float* __restrict__ ow,
                                                const float* __restrict__ xp,
                                                u16* __restrict__ lmb,
                                                u16* __restrict__ inb,
                                                u16* __restrict__ owb_,
                                                u16* __restrict__ xpb) {
    int idx = blockIdx.x * 256 + threadIdx.x;
    const float* src; u16* dst; int off;
    if (idx < 2048000)      { src = lm;  dst = lmb;  off = idx; }
    else if (idx < 2834432) { src = inw; dst = inb;  off = idx - 2048000; }
    else if (idx < 3227648) { src = ow;  dst = owb_; off = idx - 2834432; }
    else                    { src = xp;  dst = xpb;  off = idx - 3227648; }
    float4 v0 = ((const float4*)src)[off * 2];
    float4 v1 = ((const float4*)src)[off * 2 + 1];
    union { u16 h[8]; int4 v; } r;
    r.h[0] = f2bf(v0.x); r.h[1] = f2bf(v0.y); r.h[2] = f2bf(v0.z); r.h[3] = f2bf(v0.w);
    r.h[4] = f2bf(v1.x); r.h[5] = f2bf(v1.y); r.h[6] = f2bf(v1.z); r.h[7] = f2bf(v1.w);
    ((int4*)dst)[off] = r.v;
}

// ---------------------------------------------------------------------------
// embed + pos  (f32 x + bf16 shadow xb)
// ---------------------------------------------------------------------------
__global__ __launch_bounds__(256) void embed_kernel(const int* __restrict__ tok,
                                                    const float* __restrict__ pos,
                                                    const float* __restrict__ emb,
                                                    float* __restrict__ x,
                                                    u16* __restrict__ xb) {
    int idx = blockIdx.x * 256 + threadIdx.x;
    int d = idx & (DIM - 1);
    int l = (idx >> 9) & (LL - 1);
    int b = idx >> 19;
    int t = tok[b * LL + l];
    float v = emb[(size_t)t * DIM + d] + pos[l * DIM + d];
    x[idx] = v;
    xb[idx] = f2bf(v);
}

// ---------------------------------------------------------------------------
// bf16 MFMA GEMM, 128x128 tile, BK=32, 2-buffer dist-1 counted-vmcnt.
// C[M,N](f32) = A[M,K](bf16) * W[N,K](bf16)^T (+bias).
// 4 global_load_lds per wave per stage -> steady vmcnt(4), tail vmcnt(0).
// LDS 32 KB -> 5 blocks/CU.
// ---------------------------------------------------------------------------
__global__ __launch_bounds__(256) void gemm_bf16(const u16* __restrict__ A,
                                                 const u16* __restrict__ W,
                                                 const float* __restrict__ bias,
                                                 float* __restrict__ C,
                                                 int M, int N, int K,
                                                 int lda, int ldw) {
    __shared__ __align__(16) u16 As[2 * 4096];
    __shared__ __align__(16) u16 Ws[2 * 4096];
    const int t = threadIdx.x;
    const int l = t & 63;
    const int w = t >> 6;
    // bijective XCD swizzle (m204), logical order: bn-major, bm fastest
    const int nwg = gridDim.x;
    const int q = nwg >> 3, r8 = nwg & 7;
    const int xcd = blockIdx.x & 7, rank = blockIdx.x >> 3;
    const int wgid = (xcd < r8 ? xcd * (q + 1) : r8 * (q + 1) + (xcd - r8) * q) + rank;
    const int Mb = M >> 7;
    const int bm = (wgid % Mb) * 128;
    const int bn = (wgid / Mb) * 128;
    const int wm = (w >> 1) * 64;
    const int wn = (w & 1) * 64;

    f32x4 acc[4][4] = {};
    const int nt = K >> 5;

    auto STAGE = [&](int bufi, int k0) {
#pragma unroll
        for (int p = 0; p < 2; ++p) {
            const int i = (p * 4 + w) * 64 + l;     // 0..511
            const int row = i >> 2;
            const int kq = SWZ(row, i & 3);
            __builtin_amdgcn_global_load_lds(
                (const __attribute__((address_space(1))) unsigned int*)
                    (A + (size_t)(bm + row) * lda + k0 + kq * 8),
                (__attribute__((address_space(3))) unsigned int*)
                    (As + bufi * 4096 + (p * 4 + w) * 512),
                16, 0, 0);
            __builtin_amdgcn_global_load_lds(
                (const __attribute__((address_space(1))) unsigned int*)
                    (W + (size_t)(bn + row) * ldw + k0 + kq * 8),
                (__attribute__((address_space(3))) unsigned int*)
                    (Ws + bufi * 4096 + (p * 4 + w) * 512),
                16, 0, 0);
        }
    };
    auto COMPUTE = [&](int bufi) {
        const u16* Ab = As + bufi * 4096;
        const u16* Wb = Ws + bufi * 4096;
#pragma unroll
        for (int mi = 0; mi < 4; ++mi) {
            const int ar = wm + mi * 16 + (l & 15);
            bf16x8 a = *(const bf16x8*)(Ab + ar * 32 + SWZ(ar, l >> 4) * 8);
#pragma unroll
            for (int ni = 0; ni < 4; ++ni) {
                const int wr = wn + ni * 16 + (l & 15);
                bf16x8 b = *(const bf16x8*)(Wb + wr * 32 + SWZ(wr, l >> 4) * 8);
                acc[mi][ni] = __builtin_amdgcn_mfma_f32_16x16x32_bf16(b, a, acc[mi][ni], 0, 0, 0);
            }
        }
    };

    STAGE(0, 0);
    for (int tt = 0; tt < nt; ++tt) {
        if (tt + 1 < nt) {
            STAGE((tt + 1) & 1, (tt + 1) << 5);
            asm volatile("s_waitcnt vmcnt(4)\ns_barrier" ::: "memory");
        } else {
            asm volatile("s_waitcnt vmcnt(0)\ns_barrier" ::: "memory");
        }
        COMPUTE(tt & 1);
        asm volatile("s_waitcnt lgkmcnt(0)\ns_barrier" ::: "memory");
    }

#pragma unroll
    for (int mi = 0; mi < 4; ++mi) {
        const int row = bm + wm + mi * 16 + (l & 15);
#pragma unroll
        for (int ni = 0; ni < 4; ++ni) {
            const int col = bn + wn + ni * 16 + ((l >> 4) << 2);
            float4 v;
            v.x = acc[mi][ni][0]; v.y = acc[mi][ni][1];
            v.z = acc[mi][ni][2]; v.w = acc[mi][ni][3];
            if (bias != nullptr) {
                float4 b4 = *(const float4*)(bias + col);
                v.x += b4.x; v.y += b4.y; v.z += b4.z; v.w += b4.w;
            }
            *(float4*)(C + (size_t)row * N + col) = v;
        }
    }
}

// ---------------------------------------------------------------------------
// bf16 MFMA GEMM, 128M x 64N tile, BK=32, K-split, 2-buffer dist-1.
// 3 global_load_lds per wave per stage -> steady vmcnt(3), tail vmcnt(0).
// ---------------------------------------------------------------------------
__global__ __launch_bounds__(256) void gemm_n64(const u16* __restrict__ A,
                                                const u16* __restrict__ W,
                                                float* __restrict__ out,
                                                int lda, int ldw, int ldc,
                                                int KS, int pstride) {
    __shared__ __align__(16) u16 As[2 * 4096];
    __shared__ __align__(16) u16 Ws[2 * 2048];
    const int t = threadIdx.x;
    const int l = t & 63;
    const int w = t >> 6;
    const int kz = blockIdx.x;
    const int bm = blockIdx.y * 128;
    const int bnn = blockIdx.z * 64;
    const int wm = w * 32;

    f32x4 acc[2][4] = {};
    const int nt = KS >> 5;
    const int kbeg = kz * KS;

    auto STAGE = [&](int bufi, int k0) {
#pragma unroll
        for (int p = 0; p < 2; ++p) {
            const int i = p * 256 + w * 64 + l;     // 0..511
            const int row = i >> 2;
            const int kq = SWZ(row, i & 3);
            __builtin_amdgcn_global_load_lds(
                (const __attribute__((address_space(1))) unsigned int*)
                    (A + (size_t)(bm + row) * lda + k0 + kq * 8),
                (__attribute__((address_space(3))) unsigned int*)
                    (As + bufi * 4096 + (p * 256 + w * 64) * 8),
                16, 0, 0);
        }
        {
            const int i = w * 64 + l;               // 0..255
            const int row = i >> 2;
            const int kq = SWZ(row, i & 3);
            __builtin_amdgcn_global_load_lds(
                (const __attribute__((address_space(1))) unsigned int*)
                    (W + (size_t)(bnn + row) * ldw + k0 + kq * 8),
                (__attribute__((address_space(3))) unsigned int*)
                    (Ws + bufi * 2048 + (w * 64) * 8),
                16, 0, 0);
        }
    };
    auto COMPUTE = [&](int bufi) {
        const u16* Ab = As + bufi * 4096;
        const u16* Wb = Ws + bufi * 2048;
#pragma unroll
        for (int mi = 0; mi < 2; ++mi) {
            const int ar = wm + mi * 16 + (l & 15);
            bf16x8 a = *(const bf16x8*)(Ab + ar * 32 + SWZ(ar, l >> 4) * 8);
#pragma unroll
            for (int ni = 0; ni < 4; ++ni) {
                const int wr = ni * 16 + (l & 15);
                bf16x8 b = *(const bf16x8*)(Wb + wr * 32 + SWZ(wr, l >> 4) * 8);
                acc[mi][ni] = __builtin_amdgcn_mfma_f32_16x16x32_bf16(b, a, acc[mi][ni], 0, 0, 0);
            }
        }
    };

    STAGE(0, kbeg);
    for (int tt = 0; tt < nt; ++tt) {
        if (tt + 1 < nt) {
            STAGE((tt + 1) & 1, kbeg + ((tt + 1) << 5));
            asm volatile("s_waitcnt vmcnt(3)\ns_barrier" ::: "memory");
        } else {
            asm volatile("s_waitcnt vmcnt(0)\ns_barrier" ::: "memory");
        }
        COMPUTE(tt & 1);
        asm volatile("s_waitcnt lgkmcnt(0)\ns_barrier" ::: "memory");
    }

    float* op = out + (size_t)kz * pstride;
#pragma unroll
    for (int mi = 0; mi < 2; ++mi) {
        const int row = bm + wm + mi * 16 + (l & 15);
#pragma unroll
        for (int ni = 0; ni < 4; ++ni) {
            const int col = bnn + ni * 16 + ((l >> 4) << 2);
            float4 v;
            v.x = acc[mi][ni][0]; v.y = acc[mi][ni][1];
            v.z = acc[mi][ni][2]; v.w = acc[mi][ni][3];
            *(float4*)(op + (size_t)row * ldc + col) = v;
        }
    }
}

// ---------------------------------------------------------------------------
// fused: x_proj K-split reduce -> xd, then dt = softplus(xd[:,:32]@dtw^T+dtb)
// grid 128 blocks x 256 thr; block owns 16 rows.  f32 weights (no bf16 loss).
// ---------------------------------------------------------------------------
__global__ __launch_bounds__(256) void xdred_dt(const float* __restrict__ Pf,
                                                const float* __restrict__ dtw,
                                                const float* __restrict__ dtb,
                                                float* __restrict__ xd,
                                                float* __restrict__ dt) {
    __shared__ float xds[16][64];
    const int m0 = blockIdx.x * 16;
    const int t = threadIdx.x;
    for (int i = t; i < 1024; i += 256) {
        int r = i >> 6, c = i & 63;
        float s = 0.f;
#pragma unroll
        for (int kz = 0; kz < KSPLIT; ++kz)
            s += Pf[(size_t)kz * (M_ROWS * 64) + (m0 + r) * 64 + c];
        xds[r][c] = s;
        xd[(m0 + r) * 64 + c] = s;
    }
    __syncthreads();
    const int d0 = t * 4;
    float acc[16][4];
#pragma unroll
    for (int r = 0; r < 16; ++r)
#pragma unroll
        for (int j = 0; j < 4; ++j) acc[r][j] = 0.f;
#pragma unroll
    for (int qk = 0; qk < 8; ++qk) {
        float4 w0 = *(const float4*)(dtw + (d0 + 0) * DR + qk * 4);
        float4 w1 = *(const float4*)(dtw + (d0 + 1) * DR + qk * 4);
        float4 w2 = *(const float4*)(dtw + (d0 + 2) * DR + qk * 4);
        float4 w3 = *(const float4*)(dtw + (d0 + 3) * DR + qk * 4);
#pragma unroll
        for (int r = 0; r < 16; ++r) {
            float4 xv = *(const float4*)&xds[r][qk * 4];
            acc[r][0] += w0.x * xv.x + w0.y * xv.y + w0.z * xv.z + w0.w * xv.w;
            acc[r][1] += w1.x * xv.x + w1.y * xv.y + w1.z * xv.z + w1.w * xv.w;
            acc[r][2] += w2.x * xv.x + w2.y * xv.y + w2.z * xv.z + w2.w * xv.w;
            acc[r][3] += w3.x * xv.x + w3.y * xv.y + w3.z * xv.z + w3.w * xv.w;
        }
    }
    float4 bv = *(const float4*)(dtb + d0);
#pragma unroll
    for (int r = 0; r < 16; ++r) {
        float4 v;
        v.x = acc[r][0] + bv.x;
        v.y = acc[r][1] + bv.y;
        v.z = acc[r][2] + bv.z;
        v.w = acc[r][3] + bv.w;
        v.x = (v.x > 20.f) ? v.x : log1pf(__expf(v.x));
        v.y = (v.y > 20.f) ? v.y : log1pf(__expf(v.y));
        v.z = (v.z > 20.f) ? v.z : log1pf(__expf(v.z));
        v.w = (v.w > 20.f) ? v.w : log1pf(__expf(v.w));
        *(float4*)(dt + (size_t)(m0 + r) * DI + d0) = v;
    }
}

// ---------------------------------------------------------------------------
// causal depthwise conv (DC=4) + SiLU  -> xc f32 + xcb bf16
// ---------------------------------------------------------------------------
__global__ __launch_bounds__(256) void conv_silu(const float* __restrict__ xz,
                                                 const float* __restrict__ cw,
                                                 const float* __restrict__ cb,
                                                 float* __restrict__ xc,
                                                 u16* __restrict__ xcb) {
    int idx = blockIdx.x * 256 + threadIdx.x;   // B*L*DI
    int c = idx & (DI - 1);
    int l = (idx >> 10) & (LL - 1);
    int b = idx >> 20;
    float acc = cb[c];
#pragma unroll
    for (int k = 0; k < DC; ++k) {
        int ll = l + k - (DC - 1);
        if (ll >= 0)
            acc += cw[c * DC + k] * xz[((size_t)(b * LL + ll)) * (2 * DI) + c];
    }
    float v = acc / (1.f + __expf(-acc));
    xc[idx] = v;
    xcb[idx] = f2bf(v);
}

// ---------------------------------------------------------------------------
// Chunked selective scan, pass 1
// ---------------------------------------------------------------------------
__global__ __launch_bounds__(256) void scan_pass1(const float* __restrict__ xc,
                                                  const float* __restrict__ dt,
                                                  const float* __restrict__ xdbl,
                                                  const float* __restrict__ A_log,
                                                  float* __restrict__ S,
                                                  float* __restrict__ Q) {
    const int d = blockIdx.x * 256 + threadIdx.x;
    const int b = blockIdx.y;
    const int c = blockIdx.z;
    float a[DS];
#pragma unroll
    for (int q = 0; q < 4; ++q) {
        float4 al = *(const float4*)(A_log + d * DS + q * 4);
        a[q * 4 + 0] = -__expf(al.x);
        a[q * 4 + 1] = -__expf(al.y);
        a[q * 4 + 2] = -__expf(al.z);
        a[q * 4 + 3] = -__expf(al.w);
    }
    float Qr[DS];
#pragma unroll
    for (int n = 0; n < DS; ++n) Qr[n] = 0.f;
    float Ssum = 0.f;

    const int l0 = c * CHLEN;
    const float* dtp = dt + ((size_t)b * LL + l0) * DI + d;
    const float* up  = xc + ((size_t)b * LL + l0) * DI + d;
    const float* xdp = xdbl + ((size_t)b * LL + l0) * 64 + DR;

    for (int l = 0; l < CHLEN; ++l) {
        float dtv = dtp[(size_t)l * DI];
        float uv  = up[(size_t)l * DI];
        float wv = dtv * uv;
        Ssum += dtv;
#pragma unroll
        for (int q = 0; q < 4; ++q) {
            float4 Bv = *(const float4*)(xdp + l * 64 + q * 4);
            float dA0 = __expf(dtv * a[q * 4 + 0]);
            float dA1 = __expf(dtv * a[q * 4 + 1]);
            float dA2 = __expf(dtv * a[q * 4 + 2]);
            float dA3 = __expf(dtv * a[q * 4 + 3]);
            Qr[q * 4 + 0] = dA0 * Qr[q * 4 + 0] + wv * Bv.x;
            Qr[q * 4 + 1] = dA1 * Qr[q * 4 + 1] + wv * Bv.y;
            Qr[q * 4 + 2] = dA2 * Qr[q * 4 + 2] + wv * Bv.z;
            Qr[q * 4 + 3] = dA3 * Qr[q * 4 + 3] + wv * Bv.w;
        }
    }
    S[((size_t)b * CCH + c) * DI + d] = Ssum;
    float* Qp = Q + (((size_t)b * CCH + c) * DI + d) * DS;
#pragma unroll
    for (int q = 0; q < 4; ++q) {
        float4 o;
        o.x = Qr[q * 4 + 0]; o.y = Qr[q * 4 + 1];
        o.z = Qr[q * 4 + 2]; o.w = Qr[q * 4 + 3];
        *(float4*)(Qp + q * 4) = o;
    }
}

// ---------------------------------------------------------------------------
// Pass 2: sequential combine over chunks
// ---------------------------------------------------------------------------
__global__ __launch_bounds__(256) void scan_pass2(const float* __restrict__ A_log,
                                                  const float* __restrict__ S,
                                                  float* __restrict__ Q) {
    const int idx = blockIdx.x * 256 + threadIdx.x;
    const int b = idx >> 14;
    const int dn = idx & 16383;
    const int d = dn >> 4;
    const float a = -__expf(A_log[dn]);
    float h = 0.f;
    for (int c = 0; c < CCH; ++c) {
        const size_t soff = ((size_t)b * CCH + c) * DI + d;
        const size_t qoff = ((size_t)b * CCH + c) * (size_t)(DI * DS) + dn;
        float P = __expf(a * S[soff]);
        float qv = Q[qoff];
        Q[qoff] = h;
        h = P * h + qv;
    }
}

// ---------------------------------------------------------------------------
// Pass 3: per-chunk recurrence; gated bf16 output
// ---------------------------------------------------------------------------
__global__ __launch_bounds__(256) void scan_pass3(const float* __restrict__ xc,
                                                  const float* __restrict__ dt,
                                                  const float* __restrict__ xdbl,
                                                  const float* __restrict__ xz,
                                                  const float* __restrict__ A_log,
                                                  const float* __restrict__ Dpp,
                                                  const float* __restrict__ Q,
                                                  u16* __restrict__ y) {
    const int d = blockIdx.x * 256 + threadIdx.x;
    const int b = blockIdx.y;
    const int c = blockIdx.z;
    float a[DS];
#pragma unroll
    for (int q = 0; q < 4; ++q) {
        float4 al = *(const float4*)(A_log + d * DS + q * 4);
        a[q * 4 + 0] = -__expf(al.x);
        a[q * 4 + 1] = -__expf(al.y);
        a[q * 4 + 2] = -__expf(al.z);
        a[q * 4 + 3] = -__expf(al.w);
    }
    float h[DS];
    const float* Qp = Q + (((size_t)b * CCH + c) * DI + d) * DS;
#pragma unroll
    for (int q = 0; q < 4; ++q) {
        float4 hv = *(const float4*)(Qp + q * 4);
        h[q * 4 + 0] = hv.x; h[q * 4 + 1] = hv.y;
        h[q * 4 + 2] = hv.z; h[q * 4 + 3] = hv.w;
    }
    const float dp = Dpp[d];

    const int l0 = c * CHLEN;
    const float* dtp = dt + ((size_t)b * LL + l0) * DI + d;
    const float* up  = xc + ((size_t)b * LL + l0) * DI + d;
    const float* xdp = xdbl + ((size_t)b * LL + l0) * 64 + DR;
    const float* zp  = xz + ((size_t)b * LL + l0) * (2 * DI) + DI + d;
    u16* yp = y + ((size_t)b * LL + l0) * DI + d;

    for (int l = 0; l < CHLEN; ++l) {
        float dtv = dtp[(size_t)l * DI];
        float uv  = up[(size_t)l * DI];
        float wv = dtv * uv;
        float p = 0.f;
#pragma unroll
        for (int q = 0; q < 4; ++q) {
            float4 Bv = *(const float4*)(xdp + l * 64 + q * 4);
            float4 Cv = *(const float4*)(xdp + l * 64 + 16 + q * 4);
            float dA0 = __expf(dtv * a[q * 4 + 0]);
            float dA1 = __expf(dtv * a[q * 4 + 1]);
            float dA2 = __expf(dtv * a[q * 4 + 2]);
            float dA3 = __expf(dtv * a[q * 4 + 3]);
            h[q * 4 + 0] = dA0 * h[q * 4 + 0] + wv * Bv.x;
            h[q * 4 + 1] = dA1 * h[q * 4 + 1] + wv * Bv.y;
            h[q * 4 + 2] = dA2 * h[q * 4 + 2] + wv * Bv.z;
            h[q * 4 + 3] = dA3 * h[q * 4 + 3] + wv * Bv.w;
            p += h[q * 4 + 0] * Cv.x + h[q * 4 + 1] * Cv.y +
                 h[q * 4 + 2] * Cv.z + h[q * 4 + 3] * Cv.w;
        }
        float zv = zp[(size_t)l * (2 * DI)];
        float g = zv / (1.f + __expf(-zv));
        yp[(size_t)l * DI] = f2bf((p + uv * dp) * g);
    }
}

// ---------------------------------------------------------------------------
// x = LayerNorm(x + o) * g + b   (+ bf16 shadow)
// ---------------------------------------------------------------------------
__global__ __launch_bounds__(256) void add_ln(const float* __restrict__ o,
                                              float* __restrict__ x,
                                              const float* __restrict__ g,
                                              const float* __restrict__ b,
                                              u16* __restrict__ xb) {
    int m = blockIdx.x;
    int t = threadIdx.x;
    const float* xr = x + (size_t)m * DIM;
    const float* orr = o + (size_t)m * DIM;
    float v0 = xr[t] + orr[t];
    float v1 = xr[t + 256] + orr[t + 256];
    float s = v0 + v1;
    float ss = v0 * v0 + v1 * v1;
#pragma unroll
    for (int off = 32; off > 0; off >>= 1) {
        s += __shfl_down(s, off, 64);
        ss += __shfl_down(ss, off, 64);
    }
    __shared__ float sb[4], ssb[4];
    int w = t >> 6;
    if ((t & 63) == 0) { sb[w] = s; ssb[w] = ss; }
    __syncthreads();
    float stot = sb[0] + sb[1] + sb[2] + sb[3];
    float sstot = ssb[0] + ssb[1] + ssb[2] + ssb[3];
    float mean = stot * (1.f / DIM);
    float var = sstot * (1.f / DIM) - mean * mean;
    float rs = rsqrtf(var + 1e-5f);
    float* xw = x + (size_t)m * DIM;
    float o0 = (v0 - mean) * rs * g[t] + b[t];
    float o1 = (v1 - mean) * rs * g[t + 256] + b[t + 256];
    xw[t] = o0;
    xw[t + 256] = o1;
    xb[(size_t)m * DIM + t] = f2bf(o0);
    xb[(size_t)m * DIM + t + 256] = f2bf(o1);
}

// ---------------------------------------------------------------------------
extern "C" void kernel_launch(void* const* d_in, const int* in_sizes, int n_in,
                              void* d_out, int out_size, void* d_ws, size_t ws_size,
                              hipStream_t stream) {
    const int*   tokens = (const int*)d_in[0];
    const float* pos    = (const float*)d_in[1];
    const float* emb    = (const float*)d_in[2];
    const float* lm_w   = (const float*)d_in[3];
    const float* lm_b   = (const float*)d_in[4];
    const float* in_w   = (const float*)d_in[5];
    const float* cw     = (const float*)d_in[6];
    const float* cb     = (const float*)d_in[7];
    const float* xpw    = (const float*)d_in[8];
    const float* dtw    = (const float*)d_in[9];
    const float* dtb    = (const float*)d_in[10];
    const float* A_log  = (const float*)d_in[11];
    const float* Dpp    = (const float*)d_in[12];
    const float* ow     = (const float*)d_in[13];
    const float* lng    = (const float*)d_in[14];
    const float* lnb    = (const float*)d_in[15];
    float* out = (float*)d_out;

    float* ws = (float*)d_ws;
    float* x    = ws;                   // 1048576
    float* xz   = x + 1048576;          // 4194304
    float* xc   = xz + 4194304;         // 2097152
    float* xd   = xc + 2097152;         // 131072
    float* dt   = xd + 131072;          // 2097152
    float* o    = dt + 2097152;         // 1048576
    float* S    = o + 1048576;          // B*CCH*DI = 131072
    float* Qb   = S + 131072;           // B*CCH*DI*DS = 2097152
    float* Pf   = Qb + 2097152;         // KSPLIT*2048*64 = 1048576
    u16* xb     = (u16*)(Pf + 1048576); // 1048576
    u16* yb     = xb + 1048576;         // 2097152
    u16* xcb    = yb + 2097152;         // 2097152
    u16* lm_wb  = xcb + 2097152;        // 16384000
    u16* in_wb  = lm_wb + 16384000;     // 6291456
    u16* owb    = in_wb + 6291456;      // 3145728
    u16* xpwb   = owb + 3145728;        // 393216

    cast_all<<<12800, 256, 0, stream>>>(lm_w, in_w, ow, xpw,
                                        lm_wb, in_wb, owb, xpwb);

    embed_kernel<<<M_ROWS * DIM / 256, 256, 0, stream>>>(tokens, pos, emb, x, xb);

    for (int i = 0; i < NL; ++i) {
        // in_proj: (2048x2048x512)
        gemm_bf16<<<(2048 / 128) * (M_ROWS / 128), 256, 0, stream>>>(
            xb, in_wb + (size_t)i * 2048 * 512, nullptr, xz,
            M_ROWS, 2048, 512, 512, 512);
        conv_silu<<<M_ROWS * DI / 256, 256, 0, stream>>>(
            xz, cw + (size_t)i * DI * DC, cb + (size_t)i * DI, xc, xcb);
        // x_proj: (2048x64x1024), K-split 8 -> Pf
        gemm_n64<<<dim3(KSPLIT, M_ROWS / 128, 1), 256, 0, stream>>>(
            xcb, xpwb + (size_t)i * 64 * 1024, Pf,
            1024, 1024, 64, 1024 / KSPLIT, M_ROWS * 64);
        // fused K-split reduce + dt projection (f32)
        xdred_dt<<<128, 256, 0, stream>>>(
            Pf, dtw + (size_t)i * DI * DR, dtb + (size_t)i * DI, xd, dt);
        scan_pass1<<<dim3(DI / 256, BB, CCH), 256, 0, stream>>>(
            xc, dt, xd, A_log + (size_t)i * DI * DS, S, Qb);
        scan_pass2<<<(BB * DI * DS) / 256, 256, 0, stream>>>(
            A_log + (size_t)i * DI * DS, S, Qb);
        scan_pass3<<<dim3(DI / 256, BB, CCH), 256, 0, stream>>>(
            xc, dt, xd, xz, A_log + (size_t)i * DI * DS, Dpp + (size_t)i * DI, Qb, yb);
        // out_proj: (2048x512x1024)
        gemm_n64<<<dim3(1, M_ROWS / 128, 512 / 64), 256, 0, stream>>>(
            yb, owb + (size_t)i * 512 * 1024, o,
            1024, 1024, 512, 1024, 0);
        add_ln<<<M_ROWS, 256, 0, stream>>>(
            o, x, lng + (size_t)i * DIM, lnb + (size_t)i * DIM, xb);
    }

    gemm_bf16<<<(VOCAB / 128) * (M_ROWS / 128), 256, 0, stream>>>(
        xb, lm_wb, lm_b, out, M_ROWS, VOCAB, 512, 512, 512);
}

// Round 7
// 888.373 us; speedup vs baseline: 1.7128x; 1.7128x over previous
//
#include <hip/hip_runtime.h>
#include <hip/hip_bf16.h>
#include <math.h>

#define BB 2
#define LL 1024
#define DIM 512
#define NL 6
#define DI 1024
#define DS 16
#define DC 4
#define DR 32
#define VOCAB 32000
#define M_ROWS (BB * LL)   // 2048
#define CCH 64             // scan chunks
#define CHLEN (LL / CCH)   // 16
#define KSPLIT 8           // x_proj K-split

typedef unsigned short u16;
typedef __attribute__((ext_vector_type(8))) short bf16x8;
typedef __attribute__((ext_vector_type(4))) float f32x4;

__device__ __forceinline__ u16 f2bf(float f) {
    unsigned u = __float_as_uint(f);
    u += 0x7FFF + ((u >> 16) & 1);       // round-to-nearest-even
    return (u16)(u >> 16);
}
// LDS chunk swizzle: row r, 16B-chunk c -> c ^ ((r>>1)&3)  (involution)
#define SWZ(r, c) ((c) ^ (((r) >> 1) & 3))

// ---------------------------------------------------------------------------
// fused fp32 -> bf16 weight cast (lm_w, in_w, ow, xpw)
// ---------------------------------------------------------------------------
__global__ __launch_bounds__(256) void cast_all(const float* __restrict__ lm,
                                                const float* __restrict__ inw,
                                                const float* __restrict__ ow,
                                                const float* __restrict__ xp,
                                                u16* __restrict__ lmb,
                                                u16* __restrict__ inb,
                                                u16* __restrict__ owb_,
                                                u16* __restrict__ xpb) {
    int idx = blockIdx.x * 256 + threadIdx.x;
    const float* src; u16* dst; int off;
    if (idx < 2048000)      { src = lm;  dst = lmb;  off = idx; }
    else if (idx < 2834432) { src = inw; dst = inb;  off = idx - 2048000; }
    else if (idx < 3227648) { src = ow;  dst = owb_; off = idx - 2834432; }
    else                    { src = xp;  dst = xpb;  off = idx - 3227648; }
    float4 v0 = ((const float4*)src)[off * 2];
    float4 v1 = ((const float4*)src)[off * 2 + 1];
    union { u16 h[8]; int4 v; } r;
    r.h[0] = f2bf(v0.x); r.h[1] = f2bf(v0.y); r.h[2] = f2bf(v0.z); r.h[3] = f2bf(v0.w);
    r.h[4] = f2bf(v1.x); r.h[5] = f2bf(v1.y); r.h[6] = f2bf(v1.z); r.h[7] = f2bf(v1.w);
    ((int4*)dst)[off] = r.v;
}

// ---------------------------------------------------------------------------
// embed + pos  (f32 x + bf16 shadow xb)
// ---------------------------------------------------------------------------
__global__ __launch_bounds__(256) void embed_kernel(const int* __restrict__ tok,
                                                    const float* __restrict__ pos,
                                                    const float* __restrict__ emb,
                                                    float* __restrict__ x,
                                                    u16* __restrict__ xb) {
    int idx = blockIdx.x * 256 + threadIdx.x;
    int d = idx & (DIM - 1);
    int l = (idx >> 9) & (LL - 1);
    int b = idx >> 19;
    int t = tok[b * LL + l];
    float v = emb[(size_t)t * DIM + d] + pos[l * DIM + d];
    x[idx] = v;
    xb[idx] = f2bf(v);
}

// ---------------------------------------------------------------------------
// bf16 MFMA GEMM, 128x128 tile, BK=32, 2-buffer dist-1 counted-vmcnt.
// C[M,N](f32) = A[M,K](bf16) * W[N,K](bf16)^T (+bias).
// ---------------------------------------------------------------------------
__global__ __launch_bounds__(256) void gemm_bf16(const u16* __restrict__ A,
                                                 const u16* __restrict__ W,
                                                 const float* __restrict__ bias,
                                                 float* __restrict__ C,
                                                 int M, int N, int K,
                                                 int lda, int ldw) {
    __shared__ __align__(16) u16 As[2 * 4096];
    __shared__ __align__(16) u16 Ws[2 * 4096];
    const int t = threadIdx.x;
    const int l = t & 63;
    const int w = t >> 6;
    // bijective XCD swizzle (m204), logical order: bn-major, bm fastest
    const int nwg = gridDim.x;
    const int q = nwg >> 3, r8 = nwg & 7;
    const int xcd = blockIdx.x & 7, rank = blockIdx.x >> 3;
    const int wgid = (xcd < r8 ? xcd * (q + 1) : r8 * (q + 1) + (xcd - r8) * q) + rank;
    const int Mb = M >> 7;
    const int bm = (wgid % Mb) * 128;
    const int bn = (wgid / Mb) * 128;
    const int wm = (w >> 1) * 64;
    const int wn = (w & 1) * 64;

    f32x4 acc[4][4] = {};
    const int nt = K >> 5;

    auto STAGE = [&](int bufi, int k0) {
#pragma unroll
        for (int p = 0; p < 2; ++p) {
            const int i = (p * 4 + w) * 64 + l;     // 0..511
            const int row = i >> 2;
            const int kq = SWZ(row, i & 3);
            __builtin_amdgcn_global_load_lds(
                (const __attribute__((address_space(1))) unsigned int*)
                    (A + (size_t)(bm + row) * lda + k0 + kq * 8),
                (__attribute__((address_space(3))) unsigned int*)
                    (As + bufi * 4096 + (p * 4 + w) * 512),
                16, 0, 0);
            __builtin_amdgcn_global_load_lds(
                (const __attribute__((address_space(1))) unsigned int*)
                    (W + (size_t)(bn + row) * ldw + k0 + kq * 8),
                (__attribute__((address_space(3))) unsigned int*)
                    (Ws + bufi * 4096 + (p * 4 + w) * 512),
                16, 0, 0);
        }
    };
    auto COMPUTE = [&](int bufi) {
        const u16* Ab = As + bufi * 4096;
        const u16* Wb = Ws + bufi * 4096;
#pragma unroll
        for (int mi = 0; mi < 4; ++mi) {
            const int ar = wm + mi * 16 + (l & 15);
            bf16x8 a = *(const bf16x8*)(Ab + ar * 32 + SWZ(ar, l >> 4) * 8);
#pragma unroll
            for (int ni = 0; ni < 4; ++ni) {
                const int wr = wn + ni * 16 + (l & 15);
                bf16x8 b = *(const bf16x8*)(Wb + wr * 32 + SWZ(wr, l >> 4) * 8);
                acc[mi][ni] = __builtin_amdgcn_mfma_f32_16x16x32_bf16(b, a, acc[mi][ni], 0, 0, 0);
            }
        }
    };

    STAGE(0, 0);
    for (int tt = 0; tt < nt; ++tt) {
        if (tt + 1 < nt) {
            STAGE((tt + 1) & 1, (tt + 1) << 5);
            asm volatile("s_waitcnt vmcnt(4)\ns_barrier" ::: "memory");
        } else {
            asm volatile("s_waitcnt vmcnt(0)\ns_barrier" ::: "memory");
        }
        COMPUTE(tt & 1);
        asm volatile("s_waitcnt lgkmcnt(0)\ns_barrier" ::: "memory");
    }

#pragma unroll
    for (int mi = 0; mi < 4; ++mi) {
        const int row = bm + wm + mi * 16 + (l & 15);
#pragma unroll
        for (int ni = 0; ni < 4; ++ni) {
            const int col = bn + wn + ni * 16 + ((l >> 4) << 2);
            float4 v;
            v.x = acc[mi][ni][0]; v.y = acc[mi][ni][1];
            v.z = acc[mi][ni][2]; v.w = acc[mi][ni][3];
            if (bias != nullptr) {
                float4 b4 = *(const float4*)(bias + col);
                v.x += b4.x; v.y += b4.y; v.z += b4.z; v.w += b4.w;
            }
            *(float4*)(C + (size_t)row * N + col) = v;
        }
    }
}

// ---------------------------------------------------------------------------
// bf16 MFMA GEMM, 128M x 64N tile, BK=32, K-split, 2-buffer dist-1.
// ---------------------------------------------------------------------------
__global__ __launch_bounds__(256) void gemm_n64(const u16* __restrict__ A,
                                                const u16* __restrict__ W,
                                                float* __restrict__ out,
                                                int lda, int ldw, int ldc,
                                                int KS, int pstride) {
    __shared__ __align__(16) u16 As[2 * 4096];
    __shared__ __align__(16) u16 Ws[2 * 2048];
    const int t = threadIdx.x;
    const int l = t & 63;
    const int w = t >> 6;
    const int kz = blockIdx.x;
    const int bm = blockIdx.y * 128;
    const int bnn = blockIdx.z * 64;
    const int wm = w * 32;

    f32x4 acc[2][4] = {};
    const int nt = KS >> 5;
    const int kbeg = kz * KS;

    auto STAGE = [&](int bufi, int k0) {
#pragma unroll
        for (int p = 0; p < 2; ++p) {
            const int i = p * 256 + w * 64 + l;     // 0..511
            const int row = i >> 2;
            const int kq = SWZ(row, i & 3);
            __builtin_amdgcn_global_load_lds(
                (const __attribute__((address_space(1))) unsigned int*)
                    (A + (size_t)(bm + row) * lda + k0 + kq * 8),
                (__attribute__((address_space(3))) unsigned int*)
                    (As + bufi * 4096 + (p * 256 + w * 64) * 8),
                16, 0, 0);
        }
        {
            const int i = w * 64 + l;               // 0..255
            const int row = i >> 2;
            const int kq = SWZ(row, i & 3);
            __builtin_amdgcn_global_load_lds(
                (const __attribute__((address_space(1))) unsigned int*)
                    (W + (size_t)(bnn + row) * ldw + k0 + kq * 8),
                (__attribute__((address_space(3))) unsigned int*)
                    (Ws + bufi * 2048 + (w * 64) * 8),
                16, 0, 0);
        }
    };
    auto COMPUTE = [&](int bufi) {
        const u16* Ab = As + bufi * 4096;
        const u16* Wb = Ws + bufi * 2048;
#pragma unroll
        for (int mi = 0; mi < 2; ++mi) {
            const int ar = wm + mi * 16 + (l & 15);
            bf16x8 a = *(const bf16x8*)(Ab + ar * 32 + SWZ(ar, l >> 4) * 8);
#pragma unroll
            for (int ni = 0; ni < 4; ++ni) {
                const int wr = ni * 16 + (l & 15);
                bf16x8 b = *(const bf16x8*)(Wb + wr * 32 + SWZ(wr, l >> 4) * 8);
                acc[mi][ni] = __builtin_amdgcn_mfma_f32_16x16x32_bf16(b, a, acc[mi][ni], 0, 0, 0);
            }
        }
    };

    STAGE(0, kbeg);
    for (int tt = 0; tt < nt; ++tt) {
        if (tt + 1 < nt) {
            STAGE((tt + 1) & 1, kbeg + ((tt + 1) << 5));
            asm volatile("s_waitcnt vmcnt(3)\ns_barrier" ::: "memory");
        } else {
            asm volatile("s_waitcnt vmcnt(0)\ns_barrier" ::: "memory");
        }
        COMPUTE(tt & 1);
        asm volatile("s_waitcnt lgkmcnt(0)\ns_barrier" ::: "memory");
    }

    float* op = out + (size_t)kz * pstride;
#pragma unroll
    for (int mi = 0; mi < 2; ++mi) {
        const int row = bm + wm + mi * 16 + (l & 15);
#pragma unroll
        for (int ni = 0; ni < 4; ++ni) {
            const int col = bnn + ni * 16 + ((l >> 4) << 2);
            float4 v;
            v.x = acc[mi][ni][0]; v.y = acc[mi][ni][1];
            v.z = acc[mi][ni][2]; v.w = acc[mi][ni][3];
            *(float4*)(op + (size_t)row * ldc + col) = v;
        }
    }
}

// ---------------------------------------------------------------------------
// fused: per-row x_proj K-split reduce -> xd, then
// dt[m, :] = softplus(xd[m,:32] @ dtw^T + dtb).   One block per row.
// acc[4] scalars/thread -> ~30 VGPR, no spill.
// ---------------------------------------------------------------------------
__global__ __launch_bounds__(256) void xdred_dt(const float* __restrict__ Pf,
                                                const float* __restrict__ dtw,
                                                const float* __restrict__ dtb,
                                                float* __restrict__ xd,
                                                float* __restrict__ dt) {
    __shared__ float xds[64];
    const int m = blockIdx.x;
    const int t = threadIdx.x;
    if (t < 64) {
        float s = 0.f;
#pragma unroll
        for (int kz = 0; kz < KSPLIT; ++kz)
            s += Pf[(size_t)kz * (M_ROWS * 64) + m * 64 + t];
        xds[t] = s;
        xd[m * 64 + t] = s;
    }
    __syncthreads();
    const int d0 = t * 4;
    const float4 bv = *(const float4*)(dtb + d0);
    float a0 = bv.x, a1 = bv.y, a2 = bv.z, a3 = bv.w;
    const float* w0p = dtw + (size_t)(d0 + 0) * DR;
    const float* w1p = dtw + (size_t)(d0 + 1) * DR;
    const float* w2p = dtw + (size_t)(d0 + 2) * DR;
    const float* w3p = dtw + (size_t)(d0 + 3) * DR;
#pragma unroll
    for (int k = 0; k < DR; k += 4) {
        float4 xv = *(const float4*)&xds[k];
        float4 w0 = *(const float4*)(w0p + k);
        float4 w1 = *(const float4*)(w1p + k);
        float4 w2 = *(const float4*)(w2p + k);
        float4 w3 = *(const float4*)(w3p + k);
        a0 += w0.x * xv.x + w0.y * xv.y + w0.z * xv.z + w0.w * xv.w;
        a1 += w1.x * xv.x + w1.y * xv.y + w1.z * xv.z + w1.w * xv.w;
        a2 += w2.x * xv.x + w2.y * xv.y + w2.z * xv.z + w2.w * xv.w;
        a3 += w3.x * xv.x + w3.y * xv.y + w3.z * xv.z + w3.w * xv.w;
    }
    a0 = (a0 > 20.f) ? a0 : log1pf(__expf(a0));
    a1 = (a1 > 20.f) ? a1 : log1pf(__expf(a1));
    a2 = (a2 > 20.f) ? a2 : log1pf(__expf(a2));
    a3 = (a3 > 20.f) ? a3 : log1pf(__expf(a3));
    float4 v; v.x = a0; v.y = a1; v.z = a2; v.w = a3;
    *(float4*)(dt + (size_t)m * DI + d0) = v;
}

// ---------------------------------------------------------------------------
// causal depthwise conv (DC=4) + SiLU  -> xc f32 + xcb bf16
// ---------------------------------------------------------------------------
__global__ __launch_bounds__(256) void conv_silu(const float* __restrict__ xz,
                                                 const float* __restrict__ cw,
                                                 const float* __restrict__ cb,
                                                 float* __restrict__ xc,
                                                 u16* __restrict__ xcb) {
    int idx = blockIdx.x * 256 + threadIdx.x;   // B*L*DI
    int c = idx & (DI - 1);
    int l = (idx >> 10) & (LL - 1);
    int b = idx >> 20;
    float acc = cb[c];
#pragma unroll
    for (int k = 0; k < DC; ++k) {
        int ll = l + k - (DC - 1);
        if (ll >= 0)
            acc += cw[c * DC + k] * xz[((size_t)(b * LL + ll)) * (2 * DI) + c];
    }
    float v = acc / (1.f + __expf(-acc));
    xc[idx] = v;
    xcb[idx] = f2bf(v);
}

// ---------------------------------------------------------------------------
// Chunked selective scan, pass 1
// ---------------------------------------------------------------------------
__global__ __launch_bounds__(256) void scan_pass1(const float* __restrict__ xc,
                                                  const float* __restrict__ dt,
                                                  const float* __restrict__ xdbl,
                                                  const float* __restrict__ A_log,
                                                  float* __restrict__ S,
                                                  float* __restrict__ Q) {
    const int d = blockIdx.x * 256 + threadIdx.x;
    const int b = blockIdx.y;
    const int c = blockIdx.z;
    float a[DS];
#pragma unroll
    for (int q = 0; q < 4; ++q) {
        float4 al = *(const float4*)(A_log + d * DS + q * 4);
        a[q * 4 + 0] = -__expf(al.x);
        a[q * 4 + 1] = -__expf(al.y);
        a[q * 4 + 2] = -__expf(al.z);
        a[q * 4 + 3] = -__expf(al.w);
    }
    float Qr[DS];
#pragma unroll
    for (int n = 0; n < DS; ++n) Qr[n] = 0.f;
    float Ssum = 0.f;

    const int l0 = c * CHLEN;
    const float* dtp = dt + ((size_t)b * LL + l0) * DI + d;
    const float* up  = xc + ((size_t)b * LL + l0) * DI + d;
    const float* xdp = xdbl + ((size_t)b * LL + l0) * 64 + DR;

    for (int l = 0; l < CHLEN; ++l) {
        float dtv = dtp[(size_t)l * DI];
        float uv  = up[(size_t)l * DI];
        float wv = dtv * uv;
        Ssum += dtv;
#pragma unroll
        for (int q = 0; q < 4; ++q) {
            float4 Bv = *(const float4*)(xdp + l * 64 + q * 4);
            float dA0 = __expf(dtv * a[q * 4 + 0]);
            float dA1 = __expf(dtv * a[q * 4 + 1]);
            float dA2 = __expf(dtv * a[q * 4 + 2]);
            float dA3 = __expf(dtv * a[q * 4 + 3]);
            Qr[q * 4 + 0] = dA0 * Qr[q * 4 + 0] + wv * Bv.x;
            Qr[q * 4 + 1] = dA1 * Qr[q * 4 + 1] + wv * Bv.y;
            Qr[q * 4 + 2] = dA2 * Qr[q * 4 + 2] + wv * Bv.z;
            Qr[q * 4 + 3] = dA3 * Qr[q * 4 + 3] + wv * Bv.w;
        }
    }
    S[((size_t)b * CCH + c) * DI + d] = Ssum;
    float* Qp = Q + (((size_t)b * CCH + c) * DI + d) * DS;
#pragma unroll
    for (int q = 0; q < 4; ++q) {
        float4 o;
        o.x = Qr[q * 4 + 0]; o.y = Qr[q * 4 + 1];
        o.z = Qr[q * 4 + 2]; o.w = Qr[q * 4 + 3];
        *(float4*)(Qp + q * 4) = o;
    }
}

// ---------------------------------------------------------------------------
// Pass 2: sequential combine over chunks
// ---------------------------------------------------------------------------
__global__ __launch_bounds__(256) void scan_pass2(const float* __restrict__ A_log,
                                                  const float* __restrict__ S,
                                                  float* __restrict__ Q) {
    const int idx = blockIdx.x * 256 + threadIdx.x;
    const int b = idx >> 14;
    const int dn = idx & 16383;
    const int d = dn >> 4;
    const float a = -__expf(A_log[dn]);
    float h = 0.f;
    for (int c = 0; c < CCH; ++c) {
        const size_t soff = ((size_t)b * CCH + c) * DI + d;
        const size_t qoff = ((size_t)b * CCH + c) * (size_t)(DI * DS) + dn;
        float P = __expf(a * S[soff]);
        float qv = Q[qoff];
        Q[qoff] = h;
        h = P * h + qv;
    }
}

// ---------------------------------------------------------------------------
// Pass 3: per-chunk recurrence; gated bf16 output
// ---------------------------------------------------------------------------
__global__ __launch_bounds__(256) void scan_pass3(const float* __restrict__ xc,
                                                  const float* __restrict__ dt,
                                                  const float* __restrict__ xdbl,
                                                  const float* __restrict__ xz,
                                                  const float* __restrict__ A_log,
                                                  const float* __restrict__ Dpp,
                                                  const float* __restrict__ Q,
                                                  u16* __restrict__ y) {
    const int d = blockIdx.x * 256 + threadIdx.x;
    const int b = blockIdx.y;
    const int c = blockIdx.z;
    float a[DS];
#pragma unroll
    for (int q = 0; q < 4; ++q) {
        float4 al = *(const float4*)(A_log + d * DS + q * 4);
        a[q * 4 + 0] = -__expf(al.x);
        a[q * 4 + 1] = -__expf(al.y);
        a[q * 4 + 2] = -__expf(al.z);
        a[q * 4 + 3] = -__expf(al.w);
    }
    float h[DS];
    const float* Qp = Q + (((size_t)b * CCH + c) * DI + d) * DS;
#pragma unroll
    for (int q = 0; q < 4; ++q) {
        float4 hv = *(const float4*)(Qp + q * 4);
        h[q * 4 + 0] = hv.x; h[q * 4 + 1] = hv.y;
        h[q * 4 + 2] = hv.z; h[q * 4 + 3] = hv.w;
    }
    const float dp = Dpp[d];

    const int l0 = c * CHLEN;
    const float* dtp = dt + ((size_t)b * LL + l0) * DI + d;
    const float* up  = xc + ((size_t)b * LL + l0) * DI + d;
    const float* xdp = xdbl + ((size_t)b * LL + l0) * 64 + DR;
    const float* zp  = xz + ((size_t)b * LL + l0) * (2 * DI) + DI + d;
    u16* yp = y + ((size_t)b * LL + l0) * DI + d;

    for (int l = 0; l < CHLEN; ++l) {
        float dtv = dtp[(size_t)l * DI];
        float uv  = up[(size_t)l * DI];
        float wv = dtv * uv;
        float p = 0.f;
#pragma unroll
        for (int q = 0; q < 4; ++q) {
            float4 Bv = *(const float4*)(xdp + l * 64 + q * 4);
            float4 Cv = *(const float4*)(xdp + l * 64 + 16 + q * 4);
            float dA0 = __expf(dtv * a[q * 4 + 0]);
            float dA1 = __expf(dtv * a[q * 4 + 1]);
            float dA2 = __expf(dtv * a[q * 4 + 2]);
            float dA3 = __expf(dtv * a[q * 4 + 3]);
            h[q * 4 + 0] = dA0 * h[q * 4 + 0] + wv * Bv.x;
            h[q * 4 + 1] = dA1 * h[q * 4 + 1] + wv * Bv.y;
            h[q * 4 + 2] = dA2 * h[q * 4 + 2] + wv * Bv.z;
            h[q * 4 + 3] = dA3 * h[q * 4 + 3] + wv * Bv.w;
            p += h[q * 4 + 0] * Cv.x + h[q * 4 + 1] * Cv.y +
                 h[q * 4 + 2] * Cv.z + h[q * 4 + 3] * Cv.w;
        }
        float zv = zp[(size_t)l * (2 * DI)];
        float g = zv / (1.f + __expf(-zv));
        yp[(size_t)l * DI] = f2bf((p + uv * dp) * g);
    }
}

// ---------------------------------------------------------------------------
// x = LayerNorm(x + o) * g + b   (+ bf16 shadow)
// ---------------------------------------------------------------------------
__global__ __launch_bounds__(256) void add_ln(const float* __restrict__ o,
                                              float* __restrict__ x,
                                              const float* __restrict__ g,
                                              const float* __restrict__ b,
                                              u16* __restrict__ xb) {
    int m = blockIdx.x;
    int t = threadIdx.x;
    const float* xr = x + (size_t)m * DIM;
    const float* orr = o + (size_t)m * DIM;
    float v0 = xr[t] + orr[t];
    float v1 = xr[t + 256] + orr[t + 256];
    float s = v0 + v1;
    float ss = v0 * v0 + v1 * v1;
#pragma unroll
    for (int off = 32; off > 0; off >>= 1) {
        s += __shfl_down(s, off, 64);
        ss += __shfl_down(ss, off, 64);
    }
    __shared__ float sb[4], ssb[4];
    int w = t >> 6;
    if ((t & 63) == 0) { sb[w] = s; ssb[w] = ss; }
    __syncthreads();
    float stot = sb[0] + sb[1] + sb[2] + sb[3];
    float sstot = ssb[0] + ssb[1] + ssb[2] + ssb[3];
    float mean = stot * (1.f / DIM);
    float var = sstot * (1.f / DIM) - mean * mean;
    float rs = rsqrtf(var + 1e-5f);
    float* xw = x + (size_t)m * DIM;
    float o0 = (v0 - mean) * rs * g[t] + b[t];
    float o1 = (v1 - mean) * rs * g[t + 256] + b[t + 256];
    xw[t] = o0;
    xw[t + 256] = o1;
    xb[(size_t)m * DIM + t] = f2bf(o0);
    xb[(size_t)m * DIM + t + 256] = f2bf(o1);
}

// ---------------------------------------------------------------------------
extern "C" void kernel_launch(void* const* d_in, const int* in_sizes, int n_in,
                              void* d_out, int out_size, void* d_ws, size_t ws_size,
                              hipStream_t stream) {
    const int*   tokens = (const int*)d_in[0];
    const float* pos    = (const float*)d_in[1];
    const float* emb    = (const float*)d_in[2];
    const float* lm_w   = (const float*)d_in[3];
    const float* lm_b   = (const float*)d_in[4];
    const float* in_w   = (const float*)d_in[5];
    const float* cw     = (const float*)d_in[6];
    const float* cb     = (const float*)d_in[7];
    const float* xpw    = (const float*)d_in[8];
    const float* dtw    = (const float*)d_in[9];
    const float* dtb    = (const float*)d_in[10];
    const float* A_log  = (const float*)d_in[11];
    const float* Dpp    = (const float*)d_in[12];
    const float* ow     = (const float*)d_in[13];
    const float* lng    = (const float*)d_in[14];
    const float* lnb    = (const float*)d_in[15];
    float* out = (float*)d_out;

    float* ws = (float*)d_ws;
    float* x    = ws;                   // 1048576
    float* xz   = x + 1048576;          // 4194304
    float* xc   = xz + 4194304;         // 2097152
    float* xd   = xc + 2097152;         // 131072
    float* dt   = xd + 131072;          // 2097152
    float* o    = dt + 2097152;         // 1048576
    float* S    = o + 1048576;          // B*CCH*DI = 131072
    float* Qb   = S + 131072;           // B*CCH*DI*DS = 2097152
    float* Pf   = Qb + 2097152;         // KSPLIT*2048*64 = 1048576
    u16* xb     = (u16*)(Pf + 1048576); // 1048576
    u16* yb     = xb + 1048576;         // 2097152
    u16* xcb    = yb + 2097152;         // 2097152
    u16* lm_wb  = xcb + 2097152;        // 16384000
    u16* in_wb  = lm_wb + 16384000;     // 6291456
    u16* owb    = in_wb + 6291456;      // 3145728
    u16* xpwb   = owb + 3145728;        // 393216

    cast_all<<<12800, 256, 0, stream>>>(lm_w, in_w, ow, xpw,
                                        lm_wb, in_wb, owb, xpwb);

    embed_kernel<<<M_ROWS * DIM / 256, 256, 0, stream>>>(tokens, pos, emb, x, xb);

    for (int i = 0; i < NL; ++i) {
        // in_proj: (2048x2048x512)
        gemm_bf16<<<(2048 / 128) * (M_ROWS / 128), 256, 0, stream>>>(
            xb, in_wb + (size_t)i * 2048 * 512, nullptr, xz,
            M_ROWS, 2048, 512, 512, 512);
        conv_silu<<<M_ROWS * DI / 256, 256, 0, stream>>>(
            xz, cw + (size_t)i * DI * DC, cb + (size_t)i * DI, xc, xcb);
        // x_proj: (2048x64x1024), K-split 8 -> Pf
        gemm_n64<<<dim3(KSPLIT, M_ROWS / 128, 1), 256, 0, stream>>>(
            xcb, xpwb + (size_t)i * 64 * 1024, Pf,
            1024, 1024, 64, 1024 / KSPLIT, M_ROWS * 64);
        // fused per-row K-split reduce + dt projection (f32)
        xdred_dt<<<M_ROWS, 256, 0, stream>>>(
            Pf, dtw + (size_t)i * DI * DR, dtb + (size_t)i * DI, xd, dt);
        scan_pass1<<<dim3(DI / 256, BB, CCH), 256, 0, stream>>>(
            xc, dt, xd, A_log + (size_t)i * DI * DS, S, Qb);
        scan_pass2<<<(BB * DI * DS) / 256, 256, 0, stream>>>(
            A_log + (size_t)i * DI * DS, S, Qb);
        scan_pass3<<<dim3(DI / 256, BB, CCH), 256, 0, stream>>>(
            xc, dt, xd, xz, A_log + (size_t)i * DI * DS, Dpp + (size_t)i * DI, Qb, yb);
        // out_proj: (2048x512x1024)
        gemm_n64<<<dim3(1, M_ROWS / 128, 512 / 64), 256, 0, stream>>>(
            yb, owb + (size_t)i * 512 * 1024, o,
            1024, 1024, 512, 1024, 0);
        add_ln<<<M_ROWS, 256, 0, stream>>>(
            o, x, lng + (size_t)i * DIM, lnb + (size_t)i * DIM, xb);
    }

    gemm_bf16<<<(VOCAB / 128) * (M_ROWS / 128), 256, 0, stream>>>(
        xb, lm_wb, lm_b, out, M_ROWS, VOCAB, 512, 512, 512);
}

// Round 8
// 838.148 us; speedup vs baseline: 1.8154x; 1.0599x over previous
//
#include <hip/hip_runtime.h>
#include <hip/hip_bf16.h>
#include <math.h>

#define BB 2
#define LL 1024
#define DIM 512
#define NL 6
#define DI 1024
#define DS 16
#define DC 4
#define DR 32
#define VOCAB 32000
#define M_ROWS (BB * LL)   // 2048
#define CCH 64             // scan chunks
#define CHLEN (LL / CCH)   // 16
#define KSPLIT 8           // x_proj K-split
#define OSPLIT 4           // out_proj K-split

typedef unsigned short u16;
typedef __attribute__((ext_vector_type(8))) short bf16x8;
typedef __attribute__((ext_vector_type(4))) float f32x4;

__device__ __forceinline__ u16 f2bf(float f) {
    unsigned u = __float_as_uint(f);
    u += 0x7FFF + ((u >> 16) & 1);       // round-to-nearest-even
    return (u16)(u >> 16);
}
__device__ __forceinline__ float bf2f(u16 h) {
    return __uint_as_float(((unsigned)h) << 16);
}
// LDS chunk swizzle: row r, 16B-chunk c -> c ^ ((r>>1)&3)  (involution)
#define SWZ(r, c) ((c) ^ (((r) >> 1) & 3))

// ---------------------------------------------------------------------------
// fused fp32 -> bf16 weight cast (lm_w, in_w, ow, xpw)
// ---------------------------------------------------------------------------
__global__ __launch_bounds__(256) void cast_all(const float* __restrict__ lm,
                                                const float* __restrict__ inw,
                                                const float* __restrict__ ow,
                                                const float* __restrict__ xp,
                                                u16* __restrict__ lmb,
                                                u16* __restrict__ inb,
                                                u16* __restrict__ owb_,
                                                u16* __restrict__ xpb) {
    int idx = blockIdx.x * 256 + threadIdx.x;
    const float* src; u16* dst; int off;
    if (idx < 2048000)      { src = lm;  dst = lmb;  off = idx; }
    else if (idx < 2834432) { src = inw; dst = inb;  off = idx - 2048000; }
    else if (idx < 3227648) { src = ow;  dst = owb_; off = idx - 2834432; }
    else                    { src = xp;  dst = xpb;  off = idx - 3227648; }
    float4 v0 = ((const float4*)src)[off * 2];
    float4 v1 = ((const float4*)src)[off * 2 + 1];
    union { u16 h[8]; int4 v; } r;
    r.h[0] = f2bf(v0.x); r.h[1] = f2bf(v0.y); r.h[2] = f2bf(v0.z); r.h[3] = f2bf(v0.w);
    r.h[4] = f2bf(v1.x); r.h[5] = f2bf(v1.y); r.h[6] = f2bf(v1.z); r.h[7] = f2bf(v1.w);
    ((int4*)dst)[off] = r.v;
}

// ---------------------------------------------------------------------------
// embed + pos  (f32 x + bf16 shadow xb)
// ---------------------------------------------------------------------------
__global__ __launch_bounds__(256) void embed_kernel(const int* __restrict__ tok,
                                                    const float* __restrict__ pos,
                                                    const float* __restrict__ emb,
                                                    float* __restrict__ x,
                                                    u16* __restrict__ xb) {
    int idx = blockIdx.x * 256 + threadIdx.x;
    int d = idx & (DIM - 1);
    int l = (idx >> 9) & (LL - 1);
    int b = idx >> 19;
    int t = tok[b * LL + l];
    float v = emb[(size_t)t * DIM + d] + pos[l * DIM + d];
    x[idx] = v;
    xb[idx] = f2bf(v);
}

// ---------------------------------------------------------------------------
// bf16 MFMA GEMM, 128x128 tile, BK=32, 2-buffer dist-1 counted-vmcnt.
// (LM head only)  C[M,N](f32) = A * W^T (+bias)
// ---------------------------------------------------------------------------
__global__ __launch_bounds__(256) void gemm_bf16(const u16* __restrict__ A,
                                                 const u16* __restrict__ W,
                                                 const float* __restrict__ bias,
                                                 float* __restrict__ C,
                                                 int M, int N, int K,
                                                 int lda, int ldw) {
    __shared__ __align__(16) u16 As[2 * 4096];
    __shared__ __align__(16) u16 Ws[2 * 4096];
    const int t = threadIdx.x;
    const int l = t & 63;
    const int w = t >> 6;
    const int nwg = gridDim.x;
    const int q = nwg >> 3, r8 = nwg & 7;
    const int xcd = blockIdx.x & 7, rank = blockIdx.x >> 3;
    const int wgid = (xcd < r8 ? xcd * (q + 1) : r8 * (q + 1) + (xcd - r8) * q) + rank;
    const int Mb = M >> 7;
    const int bm = (wgid % Mb) * 128;
    const int bn = (wgid / Mb) * 128;
    const int wm = (w >> 1) * 64;
    const int wn = (w & 1) * 64;

    f32x4 acc[4][4] = {};
    const int nt = K >> 5;

    auto STAGE = [&](int bufi, int k0) {
#pragma unroll
        for (int p = 0; p < 2; ++p) {
            const int i = (p * 4 + w) * 64 + l;     // 0..511
            const int row = i >> 2;
            const int kq = SWZ(row, i & 3);
            __builtin_amdgcn_global_load_lds(
                (const __attribute__((address_space(1))) unsigned int*)
                    (A + (size_t)(bm + row) * lda + k0 + kq * 8),
                (__attribute__((address_space(3))) unsigned int*)
                    (As + bufi * 4096 + (p * 4 + w) * 512),
                16, 0, 0);
            __builtin_amdgcn_global_load_lds(
                (const __attribute__((address_space(1))) unsigned int*)
                    (W + (size_t)(bn + row) * ldw + k0 + kq * 8),
                (__attribute__((address_space(3))) unsigned int*)
                    (Ws + bufi * 4096 + (p * 4 + w) * 512),
                16, 0, 0);
        }
    };
    auto COMPUTE = [&](int bufi) {
        const u16* Ab = As + bufi * 4096;
        const u16* Wb = Ws + bufi * 4096;
#pragma unroll
        for (int mi = 0; mi < 4; ++mi) {
            const int ar = wm + mi * 16 + (l & 15);
            bf16x8 a = *(const bf16x8*)(Ab + ar * 32 + SWZ(ar, l >> 4) * 8);
#pragma unroll
            for (int ni = 0; ni < 4; ++ni) {
                const int wr = wn + ni * 16 + (l & 15);
                bf16x8 b = *(const bf16x8*)(Wb + wr * 32 + SWZ(wr, l >> 4) * 8);
                acc[mi][ni] = __builtin_amdgcn_mfma_f32_16x16x32_bf16(b, a, acc[mi][ni], 0, 0, 0);
            }
        }
    };

    STAGE(0, 0);
    for (int tt = 0; tt < nt; ++tt) {
        if (tt + 1 < nt) {
            STAGE((tt + 1) & 1, (tt + 1) << 5);
            asm volatile("s_waitcnt vmcnt(4)\ns_barrier" ::: "memory");
        } else {
            asm volatile("s_waitcnt vmcnt(0)\ns_barrier" ::: "memory");
        }
        COMPUTE(tt & 1);
        asm volatile("s_waitcnt lgkmcnt(0)\ns_barrier" ::: "memory");
    }

#pragma unroll
    for (int mi = 0; mi < 4; ++mi) {
        const int row = bm + wm + mi * 16 + (l & 15);
#pragma unroll
        for (int ni = 0; ni < 4; ++ni) {
            const int col = bn + wn + ni * 16 + ((l >> 4) << 2);
            float4 v;
            v.x = acc[mi][ni][0]; v.y = acc[mi][ni][1];
            v.z = acc[mi][ni][2]; v.w = acc[mi][ni][3];
            if (bias != nullptr) {
                float4 b4 = *(const float4*)(bias + col);
                v.x += b4.x; v.y += b4.y; v.z += b4.z; v.w += b4.w;
            }
            *(float4*)(C + (size_t)row * N + col) = v;
        }
    }
}

// ---------------------------------------------------------------------------
// bf16 MFMA GEMM, 128M x 64N tile, BK=32, K-split, 2-buffer dist-1.
// f32 out (out!=null) or bf16 out (outb!=null).
// ---------------------------------------------------------------------------
__global__ __launch_bounds__(256) void gemm_n64(const u16* __restrict__ A,
                                                const u16* __restrict__ W,
                                                float* __restrict__ out,
                                                u16* __restrict__ outb,
                                                int lda, int ldw, int ldc,
                                                int KS, int pstride) {
    __shared__ __align__(16) u16 As[2 * 4096];
    __shared__ __align__(16) u16 Ws[2 * 2048];
    const int t = threadIdx.x;
    const int l = t & 63;
    const int w = t >> 6;
    const int kz = blockIdx.x;
    const int bm = blockIdx.y * 128;
    const int bnn = blockIdx.z * 64;
    const int wm = w * 32;

    f32x4 acc[2][4] = {};
    const int nt = KS >> 5;
    const int kbeg = kz * KS;

    auto STAGE = [&](int bufi, int k0) {
#pragma unroll
        for (int p = 0; p < 2; ++p) {
            const int i = p * 256 + w * 64 + l;     // 0..511
            const int row = i >> 2;
            const int kq = SWZ(row, i & 3);
            __builtin_amdgcn_global_load_lds(
                (const __attribute__((address_space(1))) unsigned int*)
                    (A + (size_t)(bm + row) * lda + k0 + kq * 8),
                (__attribute__((address_space(3))) unsigned int*)
                    (As + bufi * 4096 + (p * 256 + w * 64) * 8),
                16, 0, 0);
        }
        {
            const int i = w * 64 + l;               // 0..255
            const int row = i >> 2;
            const int kq = SWZ(row, i & 3);
            __builtin_amdgcn_global_load_lds(
                (const __attribute__((address_space(1))) unsigned int*)
                    (W + (size_t)(bnn + row) * ldw + k0 + kq * 8),
                (__attribute__((address_space(3))) unsigned int*)
                    (Ws + bufi * 2048 + (w * 64) * 8),
                16, 0, 0);
        }
    };
    auto COMPUTE = [&](int bufi) {
        const u16* Ab = As + bufi * 4096;
        const u16* Wb = Ws + bufi * 2048;
#pragma unroll
        for (int mi = 0; mi < 2; ++mi) {
            const int ar = wm + mi * 16 + (l & 15);
            bf16x8 a = *(const bf16x8*)(Ab + ar * 32 + SWZ(ar, l >> 4) * 8);
#pragma unroll
            for (int ni = 0; ni < 4; ++ni) {
                const int wr = ni * 16 + (l & 15);
                bf16x8 b = *(const bf16x8*)(Wb + wr * 32 + SWZ(wr, l >> 4) * 8);
                acc[mi][ni] = __builtin_amdgcn_mfma_f32_16x16x32_bf16(b, a, acc[mi][ni], 0, 0, 0);
            }
        }
    };

    STAGE(0, kbeg);
    for (int tt = 0; tt < nt; ++tt) {
        if (tt + 1 < nt) {
            STAGE((tt + 1) & 1, kbeg + ((tt + 1) << 5));
            asm volatile("s_waitcnt vmcnt(3)\ns_barrier" ::: "memory");
        } else {
            asm volatile("s_waitcnt vmcnt(0)\ns_barrier" ::: "memory");
        }
        COMPUTE(tt & 1);
        asm volatile("s_waitcnt lgkmcnt(0)\ns_barrier" ::: "memory");
    }

    if (outb != nullptr) {
        u16* opb = outb + (size_t)kz * pstride;
#pragma unroll
        for (int mi = 0; mi < 2; ++mi) {
            const int row = bm + wm + mi * 16 + (l & 15);
#pragma unroll
            for (int ni = 0; ni < 4; ++ni) {
                const int col = bnn + ni * 16 + ((l >> 4) << 2);
                ushort4 v;
                v.x = f2bf(acc[mi][ni][0]); v.y = f2bf(acc[mi][ni][1]);
                v.z = f2bf(acc[mi][ni][2]); v.w = f2bf(acc[mi][ni][3]);
                *(ushort4*)(opb + (size_t)row * ldc + col) = v;
            }
        }
    } else {
        float* op = out + (size_t)kz * pstride;
#pragma unroll
        for (int mi = 0; mi < 2; ++mi) {
            const int row = bm + wm + mi * 16 + (l & 15);
#pragma unroll
            for (int ni = 0; ni < 4; ++ni) {
                const int col = bnn + ni * 16 + ((l >> 4) << 2);
                float4 v;
                v.x = acc[mi][ni][0]; v.y = acc[mi][ni][1];
                v.z = acc[mi][ni][2]; v.w = acc[mi][ni][3];
                *(float4*)(op + (size_t)row * ldc + col) = v;
            }
        }
    }
}

// ---------------------------------------------------------------------------
// fused: per-row x_proj K-split reduce -> xd, then dt = softplus(...)
// ---------------------------------------------------------------------------
__global__ __launch_bounds__(256) void xdred_dt(const float* __restrict__ Pf,
                                                const float* __restrict__ dtw,
                                                const float* __restrict__ dtb,
                                                float* __restrict__ xd,
                                                float* __restrict__ dt) {
    __shared__ float xds[64];
    const int m = blockIdx.x;
    const int t = threadIdx.x;
    if (t < 64) {
        float s = 0.f;
#pragma unroll
        for (int kz = 0; kz < KSPLIT; ++kz)
            s += Pf[(size_t)kz * (M_ROWS * 64) + m * 64 + t];
        xds[t] = s;
        xd[m * 64 + t] = s;
    }
    __syncthreads();
    const int d0 = t * 4;
    const float4 bv = *(const float4*)(dtb + d0);
    float a0 = bv.x, a1 = bv.y, a2 = bv.z, a3 = bv.w;
    const float* w0p = dtw + (size_t)(d0 + 0) * DR;
    const float* w1p = dtw + (size_t)(d0 + 1) * DR;
    const float* w2p = dtw + (size_t)(d0 + 2) * DR;
    const float* w3p = dtw + (size_t)(d0 + 3) * DR;
#pragma unroll
    for (int k = 0; k < DR; k += 4) {
        float4 xv = *(const float4*)&xds[k];
        float4 w0 = *(const float4*)(w0p + k);
        float4 w1 = *(const float4*)(w1p + k);
        float4 w2 = *(const float4*)(w2p + k);
        float4 w3 = *(const float4*)(w3p + k);
        a0 += w0.x * xv.x + w0.y * xv.y + w0.z * xv.z + w0.w * xv.w;
        a1 += w1.x * xv.x + w1.y * xv.y + w1.z * xv.z + w1.w * xv.w;
        a2 += w2.x * xv.x + w2.y * xv.y + w2.z * xv.z + w2.w * xv.w;
        a3 += w3.x * xv.x + w3.y * xv.y + w3.z * xv.z + w3.w * xv.w;
    }
    a0 = (a0 > 20.f) ? a0 : log1pf(__expf(a0));
    a1 = (a1 > 20.f) ? a1 : log1pf(__expf(a1));
    a2 = (a2 > 20.f) ? a2 : log1pf(__expf(a2));
    a3 = (a3 > 20.f) ? a3 : log1pf(__expf(a3));
    float4 v; v.x = a0; v.y = a1; v.z = a2; v.w = a3;
    *(float4*)(dt + (size_t)m * DI + d0) = v;
}

// ---------------------------------------------------------------------------
// causal depthwise conv (DC=4) + SiLU  (bf16 xz input) -> xc f32 + xcb bf16
// ---------------------------------------------------------------------------
__global__ __launch_bounds__(256) void conv_silu(const u16* __restrict__ xzb,
                                                 const float* __restrict__ cw,
                                                 const float* __restrict__ cb,
                                                 float* __restrict__ xc,
                                                 u16* __restrict__ xcb) {
    int idx = blockIdx.x * 256 + threadIdx.x;   // B*L*DI
    int c = idx & (DI - 1);
    int l = (idx >> 10) & (LL - 1);
    int b = idx >> 20;
    float acc = cb[c];
#pragma unroll
    for (int k = 0; k < DC; ++k) {
        int ll = l + k - (DC - 1);
        if (ll >= 0)
            acc += cw[c * DC + k] * bf2f(xzb[((size_t)(b * LL + ll)) * (2 * DI) + c]);
    }
    float v = acc / (1.f + __expf(-acc));
    xc[idx] = v;
    xcb[idx] = f2bf(v);
}

// ---------------------------------------------------------------------------
// Chunked selective scan, pass 1
// ---------------------------------------------------------------------------
__global__ __launch_bounds__(256) void scan_pass1(const float* __restrict__ xc,
                                                  const float* __restrict__ dt,
                                                  const float* __restrict__ xdbl,
                                                  const float* __restrict__ A_log,
                                                  float* __restrict__ S,
                                                  float* __restrict__ Q) {
    const int d = blockIdx.x * 256 + threadIdx.x;
    const int b = blockIdx.y;
    const int c = blockIdx.z;
    float a[DS];
#pragma unroll
    for (int q = 0; q < 4; ++q) {
        float4 al = *(const float4*)(A_log + d * DS + q * 4);
        a[q * 4 + 0] = -__expf(al.x);
        a[q * 4 + 1] = -__expf(al.y);
        a[q * 4 + 2] = -__expf(al.z);
        a[q * 4 + 3] = -__expf(al.w);
    }
    float Qr[DS];
#pragma unroll
    for (int n = 0; n < DS; ++n) Qr[n] = 0.f;
    float Ssum = 0.f;

    const int l0 = c * CHLEN;
    const float* dtp = dt + ((size_t)b * LL + l0) * DI + d;
    const float* up  = xc + ((size_t)b * LL + l0) * DI + d;
    const float* xdp = xdbl + ((size_t)b * LL + l0) * 64 + DR;

    for (int l = 0; l < CHLEN; ++l) {
        float dtv = dtp[(size_t)l * DI];
        float uv  = up[(size_t)l * DI];
        float wv = dtv * uv;
        Ssum += dtv;
#pragma unroll
        for (int q = 0; q < 4; ++q) {
            float4 Bv = *(const float4*)(xdp + l * 64 + q * 4);
            float dA0 = __expf(dtv * a[q * 4 + 0]);
            float dA1 = __expf(dtv * a[q * 4 + 1]);
            float dA2 = __expf(dtv * a[q * 4 + 2]);
            float dA3 = __expf(dtv * a[q * 4 + 3]);
            Qr[q * 4 + 0] = dA0 * Qr[q * 4 + 0] + wv * Bv.x;
            Qr[q * 4 + 1] = dA1 * Qr[q * 4 + 1] + wv * Bv.y;
            Qr[q * 4 + 2] = dA2 * Qr[q * 4 + 2] + wv * Bv.z;
            Qr[q * 4 + 3] = dA3 * Qr[q * 4 + 3] + wv * Bv.w;
        }
    }
    S[((size_t)b * CCH + c) * DI + d] = Ssum;
    float* Qp = Q + (((size_t)b * CCH + c) * DI + d) * DS;
#pragma unroll
    for (int q = 0; q < 4; ++q) {
        float4 o;
        o.x = Qr[q * 4 + 0]; o.y = Qr[q * 4 + 1];
        o.z = Qr[q * 4 + 2]; o.w = Qr[q * 4 + 3];
        *(float4*)(Qp + q * 4) = o;
    }
}

// ---------------------------------------------------------------------------
// Pass 2: sequential combine over chunks (64-thr blocks -> 512 blocks)
// ---------------------------------------------------------------------------
__global__ __launch_bounds__(64) void scan_pass2(const float* __restrict__ A_log,
                                                 const float* __restrict__ S,
                                                 float* __restrict__ Q) {
    const int idx = blockIdx.x * 64 + threadIdx.x;
    const int b = idx >> 14;
    const int dn = idx & 16383;
    const int d = dn >> 4;
    const float a = -__expf(A_log[dn]);
    float h = 0.f;
    for (int c = 0; c < CCH; ++c) {
        const size_t soff = ((size_t)b * CCH + c) * DI + d;
        const size_t qoff = ((size_t)b * CCH + c) * (size_t)(DI * DS) + dn;
        float P = __expf(a * S[soff]);
        float qv = Q[qoff];
        Q[qoff] = h;
        h = P * h + qv;
    }
}

// ---------------------------------------------------------------------------
// Pass 3: per-chunk recurrence; gated bf16 output (z from bf16 xz)
// ---------------------------------------------------------------------------
__global__ __launch_bounds__(256) void scan_pass3(const float* __restrict__ xc,
                                                  const float* __restrict__ dt,
                                                  const float* __restrict__ xdbl,
                                                  const u16* __restrict__ xzb,
                                                  const float* __restrict__ A_log,
                                                  const float* __restrict__ Dpp,
                                                  const float* __restrict__ Q,
                                                  u16* __restrict__ y) {
    const int d = blockIdx.x * 256 + threadIdx.x;
    const int b = blockIdx.y;
    const int c = blockIdx.z;
    float a[DS];
#pragma unroll
    for (int q = 0; q < 4; ++q) {
        float4 al = *(const float4*)(A_log + d * DS + q * 4);
        a[q * 4 + 0] = -__expf(al.x);
        a[q * 4 + 1] = -__expf(al.y);
        a[q * 4 + 2] = -__expf(al.z);
        a[q * 4 + 3] = -__expf(al.w);
    }
    float h[DS];
    const float* Qp = Q + (((size_t)b * CCH + c) * DI + d) * DS;
#pragma unroll
    for (int q = 0; q < 4; ++q) {
        float4 hv = *(const float4*)(Qp + q * 4);
        h[q * 4 + 0] = hv.x; h[q * 4 + 1] = hv.y;
        h[q * 4 + 2] = hv.z; h[q * 4 + 3] = hv.w;
    }
    const float dp = Dpp[d];

    const int l0 = c * CHLEN;
    const float* dtp = dt + ((size_t)b * LL + l0) * DI + d;
    const float* up  = xc + ((size_t)b * LL + l0) * DI + d;
    const float* xdp = xdbl + ((size_t)b * LL + l0) * 64 + DR;
    const u16* zp = xzb + ((size_t)b * LL + l0) * (2 * DI) + DI + d;
    u16* yp = y + ((size_t)b * LL + l0) * DI + d;

    for (int l = 0; l < CHLEN; ++l) {
        float dtv = dtp[(size_t)l * DI];
        float uv  = up[(size_t)l * DI];
        float wv = dtv * uv;
        float p = 0.f;
#pragma unroll
        for (int q = 0; q < 4; ++q) {
            float4 Bv = *(const float4*)(xdp + l * 64 + q * 4);
            float4 Cv = *(const float4*)(xdp + l * 64 + 16 + q * 4);
            float dA0 = __expf(dtv * a[q * 4 + 0]);
            float dA1 = __expf(dtv * a[q * 4 + 1]);
            float dA2 = __expf(dtv * a[q * 4 + 2]);
            float dA3 = __expf(dtv * a[q * 4 + 3]);
            h[q * 4 + 0] = dA0 * h[q * 4 + 0] + wv * Bv.x;
            h[q * 4 + 1] = dA1 * h[q * 4 + 1] + wv * Bv.y;
            h[q * 4 + 2] = dA2 * h[q * 4 + 2] + wv * Bv.z;
            h[q * 4 + 3] = dA3 * h[q * 4 + 3] + wv * Bv.w;
            p += h[q * 4 + 0] * Cv.x + h[q * 4 + 1] * Cv.y +
                 h[q * 4 + 2] * Cv.z + h[q * 4 + 3] * Cv.w;
        }
        float zv = bf2f(zp[(size_t)l * (2 * DI)]);
        float g = zv / (1.f + __expf(-zv));
        yp[(size_t)l * DI] = f2bf((p + uv * dp) * g);
    }
}

// ---------------------------------------------------------------------------
// x = LayerNorm(x + sum_kz opart) * g + b   (+ bf16 shadow)
// ---------------------------------------------------------------------------
__global__ __launch_bounds__(256) void add_ln(const float* __restrict__ opart,
                                              float* __restrict__ x,
                                              const float* __restrict__ g,
                                              const float* __restrict__ b,
                                              u16* __restrict__ xb) {
    const int PS = M_ROWS * DIM;
    int m = blockIdx.x;
    int t = threadIdx.x;
    const float* xr = x + (size_t)m * DIM;
    float v0 = xr[t];
    float v1 = xr[t + 256];
#pragma unroll
    for (int kz = 0; kz < OSPLIT; ++kz) {
        const float* op = opart + (size_t)kz * PS + (size_t)m * DIM;
        v0 += op[t];
        v1 += op[t + 256];
    }
    float s = v0 + v1;
    float ss = v0 * v0 + v1 * v1;
#pragma unroll
    for (int off = 32; off > 0; off >>= 1) {
        s += __shfl_down(s, off, 64);
        ss += __shfl_down(ss, off, 64);
    }
    __shared__ float sb[4], ssb[4];
    int w = t >> 6;
    if ((t & 63) == 0) { sb[w] = s; ssb[w] = ss; }
    __syncthreads();
    float stot = sb[0] + sb[1] + sb[2] + sb[3];
    float sstot = ssb[0] + ssb[1] + ssb[2] + ssb[3];
    float mean = stot * (1.f / DIM);
    float var = sstot * (1.f / DIM) - mean * mean;
    float rs = rsqrtf(var + 1e-5f);
    float* xw = x + (size_t)m * DIM;
    float o0 = (v0 - mean) * rs * g[t] + b[t];
    float o1 = (v1 - mean) * rs * g[t + 256] + b[t + 256];
    xw[t] = o0;
    xw[t + 256] = o1;
    xb[(size_t)m * DIM + t] = f2bf(o0);
    xb[(size_t)m * DIM + t + 256] = f2bf(o1);
}

// ---------------------------------------------------------------------------
extern "C" void kernel_launch(void* const* d_in, const int* in_sizes, int n_in,
                              void* d_out, int out_size, void* d_ws, size_t ws_size,
                              hipStream_t stream) {
    const int*   tokens = (const int*)d_in[0];
    const float* pos    = (const float*)d_in[1];
    const float* emb    = (const float*)d_in[2];
    const float* lm_w   = (const float*)d_in[3];
    const float* lm_b   = (const float*)d_in[4];
    const float* in_w   = (const float*)d_in[5];
    const float* cw     = (const float*)d_in[6];
    const float* cb     = (const float*)d_in[7];
    const float* xpw    = (const float*)d_in[8];
    const float* dtw    = (const float*)d_in[9];
    const float* dtb    = (const float*)d_in[10];
    const float* A_log  = (const float*)d_in[11];
    const float* Dpp    = (const float*)d_in[12];
    const float* ow     = (const float*)d_in[13];
    const float* lng    = (const float*)d_in[14];
    const float* lnb    = (const float*)d_in[15];
    float* out = (float*)d_out;

    float* ws = (float*)d_ws;
    float* x    = ws;                    // 1048576
    float* xc   = x + 1048576;           // 2097152
    float* xd   = xc + 2097152;          // 131072
    float* dt   = xd + 131072;           // 2097152
    float* S    = dt + 2097152;          // 131072
    float* Qb   = S + 131072;            // 2097152
    float* Pf   = Qb + 2097152;          // KSPLIT*2048*64 = 1048576
    float* Pf2  = Pf + 1048576;          // OSPLIT*2048*512 = 4194304
    u16* xzb    = (u16*)(Pf2 + 4194304); // 4194304 u16
    u16* xb     = xzb + 4194304;         // 1048576
    u16* yb     = xb + 1048576;          // 2097152
    u16* xcb    = yb + 2097152;          // 2097152
    u16* lm_wb  = xcb + 2097152;         // 16384000
    u16* in_wb  = lm_wb + 16384000;      // 6291456
    u16* owb    = in_wb + 6291456;       // 3145728
    u16* xpwb   = owb + 3145728;         // 393216

    cast_all<<<12800, 256, 0, stream>>>(lm_w, in_w, ow, xpw,
                                        lm_wb, in_wb, owb, xpwb);

    embed_kernel<<<M_ROWS * DIM / 256, 256, 0, stream>>>(tokens, pos, emb, x, xb);

    for (int i = 0; i < NL; ++i) {
        // in_proj: (2048x2048x512), 128x64 tiles, bf16 out -> 512 blocks
        gemm_n64<<<dim3(1, M_ROWS / 128, 2048 / 64), 256, 0, stream>>>(
            xb, in_wb + (size_t)i * 2048 * 512, nullptr, xzb,
            512, 512, 2048, 512, 0);
        conv_silu<<<M_ROWS * DI / 256, 256, 0, stream>>>(
            xzb, cw + (size_t)i * DI * DC, cb + (size_t)i * DI, xc, xcb);
        // x_proj: (2048x64x1024), K-split 8 -> Pf
        gemm_n64<<<dim3(KSPLIT, M_ROWS / 128, 1), 256, 0, stream>>>(
            xcb, xpwb + (size_t)i * 64 * 1024, Pf, nullptr,
            1024, 1024, 64, 1024 / KSPLIT, M_ROWS * 64);
        // fused per-row K-split reduce + dt projection (f32)
        xdred_dt<<<M_ROWS, 256, 0, stream>>>(
            Pf, dtw + (size_t)i * DI * DR, dtb + (size_t)i * DI, xd, dt);
        scan_pass1<<<dim3(DI / 256, BB, CCH), 256, 0, stream>>>(
            xc, dt, xd, A_log + (size_t)i * DI * DS, S, Qb);
        scan_pass2<<<(BB * DI * DS) / 64, 64, 0, stream>>>(
            A_log + (size_t)i * DI * DS, S, Qb);
        scan_pass3<<<dim3(DI / 256, BB, CCH), 256, 0, stream>>>(
            xc, dt, xd, xzb, A_log + (size_t)i * DI * DS, Dpp + (size_t)i * DI, Qb, yb);
        // out_proj: (2048x512x1024), K-split 4 -> Pf2 -> 512 blocks
        gemm_n64<<<dim3(OSPLIT, M_ROWS / 128, 512 / 64), 256, 0, stream>>>(
            yb, owb + (size_t)i * 512 * 1024, Pf2, nullptr,
            1024, 1024, 512, 1024 / OSPLIT, M_ROWS * 512);
        add_ln<<<M_ROWS, 256, 0, stream>>>(
            Pf2, x, lng + (size_t)i * DIM, lnb + (size_t)i * DIM, xb);
    }

    gemm_bf16<<<(VOCAB / 128) * (M_ROWS / 128), 256, 0, stream>>>(
        xb, lm_wb, lm_b, out, M_ROWS, VOCAB, 512, 512, 512);
}